// Round 2
// baseline (80.820 us; speedup 1.0000x reference)
//
#include <hip/hip_runtime.h>
#include <hip/hip_bf16.h>
#include <stdint.h>

#define BATCH 16
#define NDIM  2048
#define MDIM  2048
#define DDIM  128   // LD == RD == 128

using bf16x8 = __attribute__((ext_vector_type(8))) short;
using f32x4  = __attribute__((ext_vector_type(4))) float;

// async global->LDS, 16B per lane; LDS dest is wave-uniform base + lane*16
#define GLOAD_LDS16(g, l) __builtin_amdgcn_global_load_lds( \
    (const __attribute__((address_space(1))) void*)(g),      \
    (__attribute__((address_space(3))) void*)(l), 16, 0, 0)

__device__ __forceinline__ unsigned short f2bf(float f) {
    unsigned u = __float_as_uint(f);
    u += 0x7fffu + ((u >> 16) & 1u);   // round-to-nearest-even
    return (unsigned short)(u >> 16);
}

// ---------------------------------------------------------------------------
// Stage a 128x128 f32 tile (row stride 128 floats) into LDS as bf16, with the
// XOR-16B-chunk swizzle: logical chunk (row, ks) lands at byte
//   row*256 + (ks ^ (row & 15)) * 16.
// Each thread per iter: 32B f32 load -> 8 bf16 -> one ds_write_b128.
// ---------------------------------------------------------------------------
__device__ __forceinline__ void stage_f32_tile(const float* __restrict__ g,
                                               char* lds, int t) {
    #pragma unroll
    for (int it = 0; it < 8; ++it) {
        const int idx = it * 256 + t;           // 16B-bf16-chunk index
        const int row = idx >> 4, ks = idx & 15;
        const float4* p = (const float4*)(g + row * 128 + ks * 8);
        float4 v0 = p[0], v1 = p[1];
        bf16x8 r;
        r[0] = f2bf(v0.x); r[1] = f2bf(v0.y); r[2] = f2bf(v0.z); r[3] = f2bf(v0.w);
        r[4] = f2bf(v1.x); r[5] = f2bf(v1.y); r[6] = f2bf(v1.z); r[7] = f2bf(v1.w);
        *(bf16x8*)(lds + row * 256 + ((ks ^ (row & 15)) * 16)) = r;
    }
}

// ---------------------------------------------------------------------------
// Stage a 128x128 bf16 tile (row = 256 B contiguous) via global_load_lds.
// LDS dest is linear (chunk c at c*16); the swizzle is applied by permuting
// the SOURCE kseg, so LDS position (row, ks) holds logical kseg ks^(row&15)
// -- same relation as stage_f32_tile.
// ---------------------------------------------------------------------------
__device__ __forceinline__ void stage_bf16_gload(const char* g, char* lds, int t) {
    const int lane = t & 63, w = t >> 6;
    #pragma unroll
    for (int it = 0; it < 8; ++it) {
        const int cb = it * 256 + w * 64;       // wave-uniform chunk base
        const int c  = cb + lane;
        const int row = c >> 4, ks = c & 15;
        const int ksrc = ks ^ (row & 15);
        GLOAD_LDS16(g + (size_t)row * 256 + ksrc * 16, lds + cb * 16);
    }
}

// ---------------------------------------------------------------------------
// 128x128x128 MFMA compute on two staged bf16 tiles (A at smem, B at
// smem+32768). acc initialized here.
// ---------------------------------------------------------------------------
__device__ __forceinline__ void tile_compute_128(const char* smem,
                                                 f32x4 (&acc)[4][4], int t) {
    const int lane = t & 63, w = t >> 6;
    const int wr = w >> 1, wc = w & 1;
    const int lrow = lane & 15;
    const int lk   = lane >> 4;

    #pragma unroll
    for (int m = 0; m < 4; ++m)
        #pragma unroll
        for (int n = 0; n < 4; ++n)
            acc[m][n] = (f32x4){0.f, 0.f, 0.f, 0.f};

    #pragma unroll
    for (int ks = 0; ks < 4; ++ks) {            // 4 x K=32 substeps
        const int ksl = ks * 4 + lk;
        bf16x8 a[4], b[4];
        #pragma unroll
        for (int m = 0; m < 4; ++m) {
            const int r  = wr * 64 + m * 16 + lrow;
            const int kp = ksl ^ (r & 15);
            a[m] = *(const bf16x8*)(smem + r * 256 + kp * 16);
        }
        #pragma unroll
        for (int n = 0; n < 4; ++n) {
            const int r  = wc * 64 + n * 16 + lrow;
            const int kp = ksl ^ (r & 15);
            b[n] = *(const bf16x8*)(smem + 32768 + r * 256 + kp * 16);
        }
        #pragma unroll
        for (int m = 0; m < 4; ++m)
            #pragma unroll
            for (int n = 0; n < 4; ++n)
                acc[m][n] = __builtin_amdgcn_mfma_f32_16x16x32_bf16(
                    a[m], b[n], acc[m][n], 0, 0, 0);
    }
}

// ---------------------------------------------------------------------------
// Kernel B: cw[bm, i] = sum_j crit[bm, j] * W[i, j]  — converts f32 inputs
// in-kernel. M = 32768 flattened rows, N = 128, K = 128. Output bf16.
// ---------------------------------------------------------------------------
extern "C" __global__ __launch_bounds__(256)
void bd_cw_kernel(const float* __restrict__ crit,
                  const float* __restrict__ W,
                  unsigned short* __restrict__ cw) {
    __shared__ __align__(16) char smem[65536];
    const int t = threadIdx.x;
    const int br = blockIdx.x;  // 0..255

    stage_f32_tile(crit + (size_t)br * 128 * 128, smem, t);
    stage_f32_tile(W, smem + 32768, t);
    __syncthreads();

    f32x4 acc[4][4];
    tile_compute_128(smem, acc, t);

    const int lane = t & 63, w = t >> 6;
    const int wr = w >> 1, wc = w & 1, lrow = lane & 15, lk = lane >> 4;
    unsigned short* Cb = cw + (size_t)br * 128 * 128;
    #pragma unroll
    for (int m = 0; m < 4; ++m)
        #pragma unroll
        for (int n = 0; n < 4; ++n)
            #pragma unroll
            for (int j = 0; j < 4; ++j)
                Cb[(wr * 64 + m * 16 + lk * 4 + j) * 128 +
                   (wc * 64 + n * 16 + lrow)] = f2bf(acc[m][n][j]);
}

// ---------------------------------------------------------------------------
// Kernel C: dists[b, n, m] = sum_i data[b, n, i] * cw[b, m, i]
// A-tile: data f32 reg-staged+converted; B-tile: cw bf16 via global_load_lds
// (issued first so both stagings overlap). Output f32.
// ---------------------------------------------------------------------------
extern "C" __global__ __launch_bounds__(256)
void bd_main_kernel(const float* __restrict__ data,
                    const unsigned short* __restrict__ cw,
                    float* __restrict__ out) {
    __shared__ __align__(16) char smem[65536];
    const int t = threadIdx.x;
    const int bx = blockIdx.x;  // m tile 0..15
    const int by = blockIdx.y;  // n tile 0..15
    const int bz = blockIdx.z;  // batch 0..15

    // Issue async B staging first; A reg-staging overlaps with it.
    stage_bf16_gload((const char*)cw + ((size_t)bz * MDIM + bx * 128) * 256,
                     smem + 32768, t);
    stage_f32_tile(data + ((size_t)bz * NDIM + by * 128) * DDIM, smem, t);
    __syncthreads();

    f32x4 acc[4][4];
    tile_compute_128(smem, acc, t);

    const int lane = t & 63, w = t >> 6;
    const int wr = w >> 1, wc = w & 1, lrow = lane & 15, lk = lane >> 4;
    float* Cb = out + ((size_t)bz * NDIM + by * 128) * MDIM + bx * 128;
    #pragma unroll
    for (int m = 0; m < 4; ++m)
        #pragma unroll
        for (int n = 0; n < 4; ++n)
            #pragma unroll
            for (int j = 0; j < 4; ++j)
                Cb[(size_t)(wr * 64 + m * 16 + lk * 4 + j) * MDIM +
                   (wc * 64 + n * 16 + lrow)] = acc[m][n][j];
}

// ---------------------------------------------------------------------------
extern "C" void kernel_launch(void* const* d_in, const int* in_sizes, int n_in,
                              void* d_out, int out_size, void* d_ws, size_t ws_size,
                              hipStream_t stream) {
    const float* data = (const float*)d_in[0];  // [16,2048,128]
    const float* crit = (const float*)d_in[1];  // [16,2048,128]
    const float* W    = (const float*)d_in[2];  // [1,128,128]
    float* out = (float*)d_out;                 // [16,2048,2048]

    unsigned short* cw = (unsigned short*)d_ws; // 8 MB bf16 [16*2048, 128]

    hipLaunchKernelGGL(bd_cw_kernel, dim3(256), dim3(256), 0, stream,
                       crit, W, cw);
    hipLaunchKernelGGL(bd_main_kernel, dim3(16, 16, 16), dim3(256), 0, stream,
                       data, cw, out);
}